// Round 11
// baseline (205.294 us; speedup 1.0000x reference)
//
#include <hip/hip_runtime.h>
#include <cstdint>
#include <cstddef>

#define DEV static __device__ __forceinline__

typedef __attribute__((ext_vector_type(8))) short bf16x8;
typedef __attribute__((ext_vector_type(4))) float f32x4;

// fp32 -> bf16 round-to-nearest-even
DEV uint16_t f2bf(float f) {
  uint32_t u = __builtin_bit_cast(uint32_t, f);
  u += 0x7FFFu + ((u >> 16) & 1u);
  return (uint16_t)(u >> 16);
}

// fp32 -> bf16 truncate (P in [0,1]; cheap)
DEV uint16_t f2bf_trunc(float f) {
  return (uint16_t)(__builtin_bit_cast(uint32_t, f) >> 16);
}

DEV float bf2f(uint16_t u) {
  return __builtin_bit_cast(float, (uint32_t)u << 16);
}

// native v_exp_f32 (2^x) — avoid __exp2f name clash with glibc math.h
DEV float fexp2(float x) { return __builtin_amdgcn_exp2f(x); }

// DPP cross-lane (VALU pipe, not LDS): ctrl 0xB1=quad_perm xor1,
// 0x4E=quad_perm xor2, 0x124=row_ror:4, 0x128=row_ror:8 (row = 16 lanes)
template <int CTRL>
DEV float dppf(float v) {
  return __builtin_bit_cast(
      float, __builtin_amdgcn_update_dpp(0, __builtin_bit_cast(int, v), CTRL, 0xF, 0xF, true));
}
DEV float rowmax16(float v) {
  v = fmaxf(v, dppf<0xB1>(v));
  v = fmaxf(v, dppf<0x4E>(v));
  v = fmaxf(v, dppf<0x124>(v));
  v = fmaxf(v, dppf<0x128>(v));
  return v;
}
DEV float rowsum16(float v) {
  v += dppf<0xB1>(v);
  v += dppf<0x4E>(v);
  v += dppf<0x124>(v);
  v += dppf<0x128>(v);
  return v;
}

// async global->LDS, 16B per lane; LDS dest is wave-uniform base + lane*16
DEV void load_lds16(const void* g, void* l) {
  auto gp = reinterpret_cast<const uint32_t __attribute__((address_space(1)))*>(
      reinterpret_cast<uintptr_t>(g));
  auto lp = reinterpret_cast<uint32_t __attribute__((address_space(3)))*>(
      reinterpret_cast<uintptr_t>(l));
  __builtin_amdgcn_global_load_lds(gp, lp, 16, 0, 0);
}

// fused fp32->bf16 convert for x + 4 weights, PLUS RoPE cos/sin table build.
__global__ __launch_bounds__(256) void cvt_all(const float* __restrict__ x,
                                               const float* __restrict__ wq,
                                               const float* __restrict__ wk,
                                               const float* __restrict__ wv,
                                               const float* __restrict__ wo,
                                               const int* __restrict__ tokpos,
                                               uint16_t* __restrict__ dst,
                                               float2* __restrict__ rtab) {
  int bx = blockIdx.x;
  if (bx >= 8192) {
    int idx = (bx - 8192) * 256 + threadIdx.x;  // 0..65535
    int s = idx >> 5, f = idx & 31;
    float invf = __expf(-0.28782314f * (float)f);  // 10000^(-2f/64)
    float pos = (float)tokpos[s];
    float sn, cs;
    __sincosf(pos * invf, &sn, &cs);
    rtab[idx] = make_float2(cs, sn);
    return;
  }
  int gi = bx * 1024 + threadIdx.x * 4;
  const float* s;
  int li;
  if (gi < 4194304) {
    s = x; li = gi;
  } else {
    int j = gi - 4194304;
    int r = j >> 20;
    li = j & 1048575;
    s = (r == 0) ? wq : (r == 1) ? wk : (r == 2) ? wv : wo;
  }
  float4 v = *reinterpret_cast<const float4*>(s + li);
  ushort4 o;
  o.x = f2bf(v.x); o.y = f2bf(v.y); o.z = f2bf(v.z); o.w = f2bf(v.w);
  *reinterpret_cast<ushort4*>(dst + gi) = o;
}

// Fused QKV GEMM: C = A * Wqkv^T. All epilogues now go through an LDS
// transpose so global stores are b128 (8x fewer VMEM instrs than scalar):
// wsel 0/1 -> row-major Q/K with in-register RoPE (pairs adjacent after
// transpose; one contiguous 32B rtab read per 8 cols), 2 -> V^T [b,h,d,s].
__global__ __launch_bounds__(256) void gemm_qkv(const uint16_t* __restrict__ A,
                                                const uint16_t* __restrict__ Wqkv,
                                                uint16_t* __restrict__ QK,  // Qb; Kb at +4194304
                                                uint16_t* __restrict__ VTb,
                                                const float2* __restrict__ rtab) {
  __shared__ union {
    struct { uint16_t a[128 * 64]; uint16_t b[128 * 64]; } st;  // 32 KiB
    uint16_t t[128 * 128];                                      // epilogue transpose
  } sm;

  const int tid = threadIdx.x;
  const int lane = tid & 63, w = tid >> 6;
  const int q = lane >> 4, l16 = lane & 15;
  const int wm = w & 1, wn = w >> 1;
  const int bm = blockIdx.y, bn = blockIdx.x;
  const int wsel = bn >> 3;

  const f32x4 z4 = {0.f, 0.f, 0.f, 0.f};
  f32x4 acc[4][4];
#pragma unroll
  for (int i = 0; i < 4; ++i)
#pragma unroll
    for (int j = 0; j < 4; ++j) acc[i][j] = z4;

  const int srow = tid >> 3, sslot = tid & 7;
  const uint16_t* Ab = A + (size_t)bm * 128 * 1024;
  const uint16_t* Bb = Wqkv + (size_t)bn * 128 * 1024;

  for (int k0 = 0; k0 < 1024; k0 += 64) {
    __syncthreads();
#pragma unroll
    for (int is = 0; is < 4; ++is) {
      int row = is * 32 + srow;
      int gch = sslot ^ (row & 7);
      char* la = (char*)sm.st.a + (is * 32 + w * 8) * 128;
      char* lb = (char*)sm.st.b + (is * 32 + w * 8) * 128;
      load_lds16(Ab + (size_t)row * 1024 + k0 + gch * 8, la);
      load_lds16(Bb + (size_t)row * 1024 + k0 + gch * 8, lb);
    }
    __syncthreads();
#pragma unroll
    for (int ks = 0; ks < 2; ++ks) {
      bf16x8 af[4], bfr[4];
#pragma unroll
      for (int i = 0; i < 4; ++i) {
        int ra = wm * 64 + i * 16 + l16;
        af[i] = *reinterpret_cast<const bf16x8*>(sm.st.a + ra * 64 +
                                                 (((ks * 4 + q) ^ (ra & 7)) * 8));
        int rb = wn * 64 + i * 16 + l16;
        bfr[i] = *reinterpret_cast<const bf16x8*>(sm.st.b + rb * 64 +
                                                  (((ks * 4 + q) ^ (rb & 7)) * 8));
      }
#pragma unroll
      for (int i = 0; i < 4; ++i)
#pragma unroll
        for (int j = 0; j < 4; ++j)
          acc[i][j] =
              __builtin_amdgcn_mfma_f32_16x16x32_bf16(af[i], bfr[j], acc[i][j], 0, 0, 0);
    }
  }

  // C/D layout: col = lane&15, row = quad*4 + reg  [m89/m91 verified]
  if (wsel < 2) {
    // stage C-tile ROW-major (bf16) with 8-col chunk swizzle keyed by row
    __syncthreads();
#pragma unroll
    for (int i = 0; i < 4; ++i)
#pragma unroll
      for (int j = 0; j < 4; ++j)
#pragma unroll
        for (int r = 0; r < 4; ++r) {
          int mL = wm * 64 + i * 16 + q * 4 + r;
          int nL = wn * 64 + j * 16 + l16;
          int ch = (nL >> 3) ^ (mL & 15);
          sm.t[mL * 128 + ch * 8 + (nL & 7)] = f2bf(acc[i][j][r]);
        }
    __syncthreads();
    uint16_t* O = QK + (size_t)wsel * 4194304;
    const float scq = (wsel == 0) ? 0.18033688f : 1.0f;  // (1/8)*log2(e) into Q
#pragma unroll
    for (int it = 0; it < 8; ++it) {
      int lr = it * 16 + (tid >> 4);  // local row 0..127
      int c = tid & 15;               // 8-col chunk
      bf16x8 vv = *reinterpret_cast<const bf16x8*>(sm.t + lr * 128 +
                                                   ((c ^ (lr & 15)) * 8));
      int gm = bm * 128 + lr;
      int gn0 = bn * 128 + c * 8;
      int cn0 = gn0 & 1023;
      int f0 = (gn0 & 63) >> 1;  // 4 consecutive freqs
      const float4* rt = reinterpret_cast<const float4*>(rtab + (gm & 2047) * 32 + f0);
      float4 cs01 = rt[0];  // (c0,s0,c1,s1)
      float4 cs23 = rt[1];  // (c2,s2,c3,s3)
      float v0 = bf2f((uint16_t)vv[0]), v1 = bf2f((uint16_t)vv[1]);
      float v2 = bf2f((uint16_t)vv[2]), v3 = bf2f((uint16_t)vv[3]);
      float v4 = bf2f((uint16_t)vv[4]), v5 = bf2f((uint16_t)vv[5]);
      float v6 = bf2f((uint16_t)vv[6]), v7 = bf2f((uint16_t)vv[7]);
      ushort4 o0, o1;
      o0.x = f2bf((v0 * cs01.x - v1 * cs01.y) * scq);
      o0.y = f2bf((v0 * cs01.y + v1 * cs01.x) * scq);
      o0.z = f2bf((v2 * cs01.z - v3 * cs01.w) * scq);
      o0.w = f2bf((v2 * cs01.w + v3 * cs01.z) * scq);
      o1.x = f2bf((v4 * cs23.x - v5 * cs23.y) * scq);
      o1.y = f2bf((v4 * cs23.y + v5 * cs23.x) * scq);
      o1.z = f2bf((v6 * cs23.z - v7 * cs23.w) * scq);
      o1.w = f2bf((v6 * cs23.w + v7 * cs23.z) * scq);
      ushort4* dst = reinterpret_cast<ushort4*>(O + (size_t)gm * 1024 + cn0);
      dst[0] = o0;
      dst[1] = o1;
    }
  } else {
    // V^T [b,h,d,s]
    const int bnv = bn & 7;
    __syncthreads();
#pragma unroll
    for (int i = 0; i < 4; ++i)
#pragma unroll
      for (int j = 0; j < 4; ++j)
#pragma unroll
        for (int r = 0; r < 4; ++r) {
          int mL = wm * 64 + i * 16 + q * 4 + r;
          int nL = wn * 64 + j * 16 + l16;
          int ch = (mL >> 3) ^ (nL & 15);
          sm.t[nL * 128 + ch * 8 + (mL & 7)] = f2bf(acc[i][j][r]);
        }
    __syncthreads();
    const int b = (bm * 128) >> 11;
    const int sblk = (bm * 128) & 2047;
#pragma unroll
    for (int it = 0; it < 8; ++it) {
      int nL = it * 16 + (tid >> 4);
      int mch = tid & 15;
      int slot = mch ^ (nL & 15);
      bf16x8 vv = *reinterpret_cast<const bf16x8*>(sm.t + nL * 128 + slot * 8);
      int gn = bnv * 128 + nL;
      int h = gn >> 6, d = gn & 63;
      *reinterpret_cast<bf16x8*>(VTb + ((size_t)((b * 16 + h) * 64 + d)) * 2048 + sblk +
                                 mch * 8) = vv;
    }
  }
}

// Output projection: C = A * Wo^T fp32. 128x64 tile -> grid (16, 32) = 512
// blocks. Epilogue via LDS transpose -> float4 stores (4x fewer VMEM instrs).
__global__ __launch_bounds__(256) void gemm_out(const uint16_t* __restrict__ A,
                                                const uint16_t* __restrict__ Bw,
                                                float* __restrict__ O) {
  __shared__ union {
    struct { uint16_t sa[128 * 64]; uint16_t sb[64 * 64]; } s;  // 24 KiB
    float t[128 * 64];                                          // 32 KiB epilogue
  } sm;

  const int tid = threadIdx.x;
  const int lane = tid & 63, w = tid >> 6;
  const int q = lane >> 4, l16 = lane & 15;
  const int bm = blockIdx.y, bn = blockIdx.x;

  const f32x4 z4 = {0.f, 0.f, 0.f, 0.f};
  f32x4 acc[2][4];
#pragma unroll
  for (int i = 0; i < 2; ++i)
#pragma unroll
    for (int j = 0; j < 4; ++j) acc[i][j] = z4;

  const int srow = tid >> 3, sslot = tid & 7;
  const uint16_t* Ab = A + (size_t)bm * 128 * 1024;
  const uint16_t* Bb = Bw + (size_t)bn * 64 * 1024;

  for (int k0 = 0; k0 < 1024; k0 += 64) {
    __syncthreads();
#pragma unroll
    for (int is = 0; is < 4; ++is) {
      int row = is * 32 + srow;
      int gch = sslot ^ (row & 7);
      load_lds16(Ab + (size_t)row * 1024 + k0 + gch * 8,
                 (char*)sm.s.sa + (is * 32 + w * 8) * 128);
    }
#pragma unroll
    for (int is = 0; is < 2; ++is) {
      int row = is * 32 + srow;
      int gch = sslot ^ (row & 7);
      load_lds16(Bb + (size_t)row * 1024 + k0 + gch * 8,
                 (char*)sm.s.sb + (is * 32 + w * 8) * 128);
    }
    __syncthreads();
#pragma unroll
    for (int ks = 0; ks < 2; ++ks) {
      bf16x8 af[2], bfr[4];
#pragma unroll
      for (int i = 0; i < 2; ++i) {
        int ra = w * 32 + i * 16 + l16;
        af[i] = *reinterpret_cast<const bf16x8*>(sm.s.sa + ra * 64 +
                                                 (((ks * 4 + q) ^ (ra & 7)) * 8));
      }
#pragma unroll
      for (int j = 0; j < 4; ++j) {
        int rb = j * 16 + l16;
        bfr[j] = *reinterpret_cast<const bf16x8*>(sm.s.sb + rb * 64 +
                                                  (((ks * 4 + q) ^ (rb & 7)) * 8));
      }
#pragma unroll
      for (int i = 0; i < 2; ++i)
#pragma unroll
        for (int j = 0; j < 4; ++j)
          acc[i][j] =
              __builtin_amdgcn_mfma_f32_16x16x32_bf16(af[i], bfr[j], acc[i][j], 0, 0, 0);
    }
  }

  // stage fp32 C-tile row-major with 4-col chunk swizzle, then float4 stores
  __syncthreads();
#pragma unroll
  for (int i = 0; i < 2; ++i)
#pragma unroll
    for (int j = 0; j < 4; ++j)
#pragma unroll
      for (int r = 0; r < 4; ++r) {
        int mL = w * 32 + i * 16 + q * 4 + r;
        int nL = j * 16 + l16;
        int ch = (nL >> 2) ^ (mL & 15);
        sm.t[mL * 64 + ch * 4 + (nL & 3)] = acc[i][j][r];
      }
  __syncthreads();
#pragma unroll
  for (int it = 0; it < 8; ++it) {
    int lr = it * 16 + (tid >> 4);  // local row 0..127
    int c = tid & 15;               // 4-col chunk
    float4 vv = *reinterpret_cast<const float4*>(sm.t + lr * 64 + ((c ^ (lr & 15)) * 4));
    *reinterpret_cast<float4*>(O + (size_t)(bm * 128 + lr) * 1024 + bn * 64 + c * 4) = vv;
  }
}

// Flash attention v8 (unchanged from R10): BK=128 dbuf LDS staging, per-lane
// li, balanced pairing, DPP row reductions. Q pre-scaled by (1/8)log2e.
__global__ __launch_bounds__(256) void flash_attn(const uint16_t* __restrict__ Q,
                                                  const uint16_t* __restrict__ K,
                                                  const uint16_t* __restrict__ VT,
                                                  uint16_t* __restrict__ AO) {
  __shared__ uint16_t ksm[2][128 * 64];  // 32 KiB (rows=s, 128B/row, 8-chunk swz)
  __shared__ uint16_t vsm[2][64 * 128];  // 32 KiB (rows=d, 256B/row, 16-chunk swz)
  __shared__ uint16_t psm[4][16 * 128];  // 16 KiB per-wave P (256B/row, 16-chunk swz)

  const int tid = threadIdx.x;
  const int lane = tid & 63, w = tid >> 6;
  const int q = lane >> 4, l16 = lane & 15;
  const int p = blockIdx.x;   // pair index 0..15 -> tiles {p, 31-p}
  const int bh = blockIdx.y;
  const int b = bh >> 4, h = bh & 15;

  const size_t baseBS = (size_t)b * 2048 * 1024 + h * 64;
  const size_t baseVT = (size_t)bh * 64 * 2048;
  uint16_t* pw = psm[w];
  const f32x4 z4 = {0.f, 0.f, 0.f, 0.f};

  auto stage = [&](int buf, int kt) {
#pragma unroll
    for (int is = 0; is < 4; ++is) {
      int row = is * 32 + (tid >> 3);
      int gch = (tid & 7) ^ (row & 7);
      load_lds16(K + baseBS + (size_t)(kt * 128 + row) * 1024 + gch * 8,
                 (char*)ksm[buf] + (is * 32 + w * 8) * 128);
    }
#pragma unroll
    for (int is = 0; is < 4; ++is) {
      int row = is * 16 + (tid >> 4);
      int gch = (tid & 15) ^ (row & 15);
      load_lds16(VT + baseVT + (size_t)row * 2048 + kt * 128 + gch * 8,
                 (char*)vsm[buf] + (is * 16 + w * 4) * 256);
    }
  };

  for (int t = 0; t < 2; ++t) {
    const int qt = t ? (31 - p) : p;
    const int r0 = qt * 64 + w * 16;
    const int nkt = (qt + 2) >> 1;

    bf16x8 qf[2];
#pragma unroll
    for (int ks = 0; ks < 2; ++ks)
      qf[ks] = *reinterpret_cast<const bf16x8*>(
          Q + baseBS + (size_t)(r0 + l16) * 1024 + ks * 32 + q * 8);

    f32x4 oa[4];
#pragma unroll
    for (int di = 0; di < 4; ++di) oa[di] = z4;
    float m2[4], li[4];
#pragma unroll
    for (int r = 0; r < 4; ++r) { m2[r] = -1e30f; li[r] = 0.f; }

    __syncthreads();
    stage(0, 0);

    for (int kt = 0; kt < nkt; ++kt) {
      const int cur = kt & 1;
      __syncthreads();
      if (kt + 1 < nkt) stage(cur ^ 1, kt + 1);

      f32x4 sc[8];
#pragma unroll
      for (int nj = 0; nj < 8; ++nj) sc[nj] = z4;
#pragma unroll
      for (int ks = 0; ks < 2; ++ks) {
        bf16x8 kf[8];
#pragma unroll
        for (int nj = 0; nj < 8; ++nj) {
          int rk = nj * 16 + l16;
          kf[nj] = *reinterpret_cast<const bf16x8*>(ksm[cur] + rk * 64 +
                                                    (((ks * 4 + q) ^ (rk & 7)) * 8));
        }
#pragma unroll
        for (int nj = 0; nj < 8; ++nj)
          sc[nj] = __builtin_amdgcn_mfma_f32_16x16x32_bf16(qf[ks], kf[nj], sc[nj], 0, 0, 0);
      }

      if (kt == nkt - 1) {
#pragma unroll
        for (int nj = 0; nj < 8; ++nj)
#pragma unroll
          for (int r = 0; r < 4; ++r) {
            int col = kt * 128 + nj * 16 + l16;
            int row = r0 + q * 4 + r;
            if (col > row) sc[nj][r] = -1e30f;
          }
      }

      float alpha[4];
#pragma unroll
      for (int r = 0; r < 4; ++r) {
        float v = fmaxf(fmaxf(fmaxf(sc[0][r], sc[1][r]), fmaxf(sc[2][r], sc[3][r])),
                        fmaxf(fmaxf(sc[4][r], sc[5][r]), fmaxf(sc[6][r], sc[7][r])));
        v = rowmax16(v);
        float mn = fmaxf(m2[r], v);
        alpha[r] = fexp2(m2[r] - mn);
        m2[r] = mn;
        li[r] *= alpha[r];
      }

#pragma unroll
      for (int nj = 0; nj < 8; ++nj)
#pragma unroll
        for (int r = 0; r < 4; ++r) {
          float pv = fexp2(sc[nj][r] - m2[r]);
          li[r] += pv;
          int pr = q * 4 + r;
          int pc = nj * 16 + l16;
          pw[pr * 128 + (((pc >> 3) ^ pr) * 8) + (pc & 7)] = f2bf_trunc(pv);
        }

#pragma unroll
      for (int di = 0; di < 4; ++di)
#pragma unroll
        for (int r = 0; r < 4; ++r) oa[di][r] *= alpha[r];

#pragma unroll
      for (int ks = 0; ks < 4; ++ks) {
        bf16x8 pf = *reinterpret_cast<const bf16x8*>(pw + l16 * 128 +
                                                     (((ks * 4 + q) ^ l16) * 8));
        bf16x8 vf[4];
#pragma unroll
        for (int di = 0; di < 4; ++di) {
          int vr = di * 16 + l16;
          vf[di] = *reinterpret_cast<const bf16x8*>(vsm[cur] + vr * 128 +
                                                    (((ks * 4 + q) ^ (vr & 15)) * 8));
        }
#pragma unroll
        for (int di = 0; di < 4; ++di)
          oa[di] = __builtin_amdgcn_mfma_f32_16x16x32_bf16(pf, vf[di], oa[di], 0, 0, 0);
      }
    }

#pragma unroll
    for (int r = 0; r < 4; ++r) li[r] = rowsum16(li[r]);

#pragma unroll
    for (int r = 0; r < 4; ++r) {
      float inv = 1.f / li[r];
      int gm = r0 + q * 4 + r;
#pragma unroll
      for (int di = 0; di < 4; ++di)
        AO[baseBS + (size_t)gm * 1024 + di * 16 + l16] = f2bf(oa[di][r] * inv);
    }
  }
}

extern "C" void kernel_launch(void* const* d_in, const int* in_sizes, int n_in,
                              void* d_out, int out_size, void* d_ws, size_t ws_size,
                              hipStream_t stream) {
  (void)in_sizes; (void)n_in; (void)out_size; (void)ws_size;
  const float* x = (const float*)d_in[0];
  const int* tokpos = (const int*)d_in[1];
  const float* wq = (const float*)d_in[2];
  const float* wk = (const float*)d_in[3];
  const float* wv = (const float*)d_in[4];
  const float* wo = (const float*)d_in[5];
  float* out = (float*)d_out;

  // workspace layout (bf16 elements) — total 48 MiB (no overflow).
  uint16_t* ws = (uint16_t*)d_ws;
  uint16_t* xb = ws;                   // 4096*1024
  uint16_t* wqb = xb + 4194304;        // wq|wk|wv|wo contiguous, 1M each
  uint16_t* wob = wqb + 3145728;
  uint16_t* Qb = wob + 1048576;        // [b,s,h,d]; Kb at +4194304
  uint16_t* VTb = Qb + 8388608;        // [b,h,d,s]
  uint16_t* AOb = VTb + 4194304;       // [b,s,h,d]
  // rtab OVERLAPS the AOb region (512 KiB at its base): built by cvt_all,
  // read by gemm_qkv, dead before flash_attn overwrites all of AOb.
  float2* rtab = (float2*)AOb;

  cvt_all<<<8448, 256, 0, stream>>>(x, wq, wk, wv, wo, tokpos, xb, rtab);

  gemm_qkv<<<dim3(24, 32), 256, 0, stream>>>(xb, wqb, Qb, VTb, rtab);

  flash_attn<<<dim3(16, 32), 256, 0, stream>>>(Qb, Qb + 4194304, VTb, AOb);

  gemm_out<<<dim3(16, 32), 256, 0, stream>>>(AOb, wob, out);
}

// Round 12
// 194.037 us; speedup vs baseline: 1.0580x; 1.0580x over previous
//
#include <hip/hip_runtime.h>
#include <cstdint>
#include <cstddef>

#define DEV static __device__ __forceinline__

typedef __attribute__((ext_vector_type(8))) short bf16x8;
typedef __attribute__((ext_vector_type(4))) float f32x4;

// fp32 -> bf16 round-to-nearest-even
DEV uint16_t f2bf(float f) {
  uint32_t u = __builtin_bit_cast(uint32_t, f);
  u += 0x7FFFu + ((u >> 16) & 1u);
  return (uint16_t)(u >> 16);
}

// fp32 -> bf16 truncate (P in [0,1]; cheap)
DEV uint16_t f2bf_trunc(float f) {
  return (uint16_t)(__builtin_bit_cast(uint32_t, f) >> 16);
}

// native v_exp_f32 (2^x) — avoid __exp2f name clash with glibc math.h
DEV float fexp2(float x) { return __builtin_amdgcn_exp2f(x); }

// DPP cross-lane (VALU pipe, not LDS): ctrl 0xB1=quad_perm xor1,
// 0x4E=quad_perm xor2, 0x124=row_ror:4, 0x128=row_ror:8 (row = 16 lanes)
template <int CTRL>
DEV float dppf(float v) {
  return __builtin_bit_cast(
      float, __builtin_amdgcn_update_dpp(0, __builtin_bit_cast(int, v), CTRL, 0xF, 0xF, true));
}
DEV float rowmax16(float v) {
  v = fmaxf(v, dppf<0xB1>(v));
  v = fmaxf(v, dppf<0x4E>(v));
  v = fmaxf(v, dppf<0x124>(v));
  v = fmaxf(v, dppf<0x128>(v));
  return v;
}
DEV float rowsum16(float v) {
  v += dppf<0xB1>(v);
  v += dppf<0x4E>(v);
  v += dppf<0x124>(v);
  v += dppf<0x128>(v);
  return v;
}

// async global->LDS, 16B per lane; LDS dest is wave-uniform base + lane*16
DEV void load_lds16(const void* g, void* l) {
  auto gp = reinterpret_cast<const uint32_t __attribute__((address_space(1)))*>(
      reinterpret_cast<uintptr_t>(g));
  auto lp = reinterpret_cast<uint32_t __attribute__((address_space(3)))*>(
      reinterpret_cast<uintptr_t>(l));
  __builtin_amdgcn_global_load_lds(gp, lp, 16, 0, 0);
}

// fused fp32->bf16 convert for x + 4 weights, PLUS RoPE cos/sin table build.
__global__ __launch_bounds__(256) void cvt_all(const float* __restrict__ x,
                                               const float* __restrict__ wq,
                                               const float* __restrict__ wk,
                                               const float* __restrict__ wv,
                                               const float* __restrict__ wo,
                                               const int* __restrict__ tokpos,
                                               uint16_t* __restrict__ dst,
                                               float2* __restrict__ rtab) {
  int bx = blockIdx.x;
  if (bx >= 8192) {
    int idx = (bx - 8192) * 256 + threadIdx.x;  // 0..65535
    int s = idx >> 5, f = idx & 31;
    float invf = __expf(-0.28782314f * (float)f);  // 10000^(-2f/64)
    float pos = (float)tokpos[s];
    float sn, cs;
    __sincosf(pos * invf, &sn, &cs);
    rtab[idx] = make_float2(cs, sn);
    return;
  }
  int gi = bx * 1024 + threadIdx.x * 4;
  const float* s;
  int li;
  if (gi < 4194304) {
    s = x; li = gi;
  } else {
    int j = gi - 4194304;
    int r = j >> 20;
    li = j & 1048575;
    s = (r == 0) ? wq : (r == 1) ? wk : (r == 2) ? wv : wo;
  }
  float4 v = *reinterpret_cast<const float4*>(s + li);
  ushort4 o;
  o.x = f2bf(v.x); o.y = f2bf(v.y); o.z = f2bf(v.z); o.w = f2bf(v.w);
  *reinterpret_cast<ushort4*>(dst + gi) = o;
}

// Fused QKV GEMM (R10 version — scattered-store epilogue; LDS-transpose variant
// regressed in R11: scalar stores are fire-and-forget, transpose added barriers).
__global__ __launch_bounds__(256) void gemm_qkv(const uint16_t* __restrict__ A,
                                                const uint16_t* __restrict__ Wqkv,
                                                uint16_t* __restrict__ QK,  // Qb; Kb at +4194304
                                                uint16_t* __restrict__ VTb,
                                                const float2* __restrict__ rtab) {
  __shared__ union {
    struct { uint16_t a[128 * 64]; uint16_t b[128 * 64]; } st;  // 32 KiB
    uint16_t t[128 * 128];                                      // epilogue transpose
  } sm;

  const int tid = threadIdx.x;
  const int lane = tid & 63, w = tid >> 6;
  const int q = lane >> 4, l16 = lane & 15;
  const int wm = w & 1, wn = w >> 1;
  const int bm = blockIdx.y, bn = blockIdx.x;
  const int wsel = bn >> 3;

  const f32x4 z4 = {0.f, 0.f, 0.f, 0.f};
  f32x4 acc[4][4];
#pragma unroll
  for (int i = 0; i < 4; ++i)
#pragma unroll
    for (int j = 0; j < 4; ++j) acc[i][j] = z4;

  const int srow = tid >> 3, sslot = tid & 7;
  const uint16_t* Ab = A + (size_t)bm * 128 * 1024;
  const uint16_t* Bb = Wqkv + (size_t)bn * 128 * 1024;

  for (int k0 = 0; k0 < 1024; k0 += 64) {
    __syncthreads();
#pragma unroll
    for (int is = 0; is < 4; ++is) {
      int row = is * 32 + srow;
      int gch = sslot ^ (row & 7);
      char* la = (char*)sm.st.a + (is * 32 + w * 8) * 128;
      char* lb = (char*)sm.st.b + (is * 32 + w * 8) * 128;
      load_lds16(Ab + (size_t)row * 1024 + k0 + gch * 8, la);
      load_lds16(Bb + (size_t)row * 1024 + k0 + gch * 8, lb);
    }
    __syncthreads();
#pragma unroll
    for (int ks = 0; ks < 2; ++ks) {
      bf16x8 af[4], bfr[4];
#pragma unroll
      for (int i = 0; i < 4; ++i) {
        int ra = wm * 64 + i * 16 + l16;
        af[i] = *reinterpret_cast<const bf16x8*>(sm.st.a + ra * 64 +
                                                 (((ks * 4 + q) ^ (ra & 7)) * 8));
        int rb = wn * 64 + i * 16 + l16;
        bfr[i] = *reinterpret_cast<const bf16x8*>(sm.st.b + rb * 64 +
                                                  (((ks * 4 + q) ^ (rb & 7)) * 8));
      }
#pragma unroll
      for (int i = 0; i < 4; ++i)
#pragma unroll
        for (int j = 0; j < 4; ++j)
          acc[i][j] =
              __builtin_amdgcn_mfma_f32_16x16x32_bf16(af[i], bfr[j], acc[i][j], 0, 0, 0);
    }
  }

  // C/D layout: col = lane&15, row = quad*4 + reg  [m89/m91 verified]
  if (wsel < 2) {
    uint16_t* O = QK + (size_t)wsel * 4194304;
    const float scq = (wsel == 0) ? 0.18033688f : 1.0f;  // (1/8)*log2(e) into Q
#pragma unroll
    for (int j = 0; j < 4; ++j) {
      int gn = bn * 128 + wn * 64 + j * 16 + l16;
      int cn = gn & 1023;
      int f = (gn & 63) >> 1;
      float sgn = (lane & 1) ? 1.f : -1.f;
#pragma unroll
      for (int i = 0; i < 4; ++i) {
#pragma unroll
        for (int r = 0; r < 4; ++r) {
          int gm = bm * 128 + wm * 64 + i * 16 + q * 4 + r;
          float2 cssn = rtab[(gm & 2047) * 32 + f];
          float v = acc[i][j][r];
          float o = dppf<0xB1>(v);  // pair-exchange (xor lane 1) via DPP
          O[(size_t)gm * 1024 + cn] = f2bf((v * cssn.x + sgn * o * cssn.y) * scq);
        }
      }
    }
  } else {
    // V^T [b,h,d,s]
    const int bnv = bn & 7;
    __syncthreads();
#pragma unroll
    for (int i = 0; i < 4; ++i)
#pragma unroll
      for (int j = 0; j < 4; ++j)
#pragma unroll
        for (int r = 0; r < 4; ++r) {
          int mL = wm * 64 + i * 16 + q * 4 + r;
          int nL = wn * 64 + j * 16 + l16;
          int ch = (mL >> 3) ^ (nL & 15);
          sm.t[nL * 128 + ch * 8 + (mL & 7)] = f2bf(acc[i][j][r]);
        }
    __syncthreads();
    const int b = (bm * 128) >> 11;
    const int sblk = (bm * 128) & 2047;
#pragma unroll
    for (int it = 0; it < 8; ++it) {
      int nL = it * 16 + (tid >> 4);
      int mch = tid & 15;
      int slot = mch ^ (nL & 15);
      bf16x8 vv = *reinterpret_cast<const bf16x8*>(sm.t + nL * 128 + slot * 8);
      int gn = bnv * 128 + nL;
      int h = gn >> 6, d = gn & 63;
      *reinterpret_cast<bf16x8*>(VTb + ((size_t)((b * 16 + h) * 64 + d)) * 2048 + sblk +
                                 mch * 8) = vv;
    }
  }
}

// Output projection (R10 version): C = A * Wo^T fp32, 128x64 tile, scalar stores.
__global__ __launch_bounds__(256) void gemm_out(const uint16_t* __restrict__ A,
                                                const uint16_t* __restrict__ Bw,
                                                float* __restrict__ O) {
  __shared__ uint16_t sa[128 * 64];  // 16 KiB
  __shared__ uint16_t sb[64 * 64];   // 8 KiB

  const int tid = threadIdx.x;
  const int lane = tid & 63, w = tid >> 6;
  const int q = lane >> 4, l16 = lane & 15;
  const int bm = blockIdx.y, bn = blockIdx.x;

  const f32x4 z4 = {0.f, 0.f, 0.f, 0.f};
  f32x4 acc[2][4];
#pragma unroll
  for (int i = 0; i < 2; ++i)
#pragma unroll
    for (int j = 0; j < 4; ++j) acc[i][j] = z4;

  const int srow = tid >> 3, sslot = tid & 7;
  const uint16_t* Ab = A + (size_t)bm * 128 * 1024;
  const uint16_t* Bb = Bw + (size_t)bn * 64 * 1024;

  for (int k0 = 0; k0 < 1024; k0 += 64) {
    __syncthreads();
#pragma unroll
    for (int is = 0; is < 4; ++is) {
      int row = is * 32 + srow;
      int gch = sslot ^ (row & 7);
      load_lds16(Ab + (size_t)row * 1024 + k0 + gch * 8,
                 (char*)sa + (is * 32 + w * 8) * 128);
    }
#pragma unroll
    for (int is = 0; is < 2; ++is) {
      int row = is * 32 + srow;
      int gch = sslot ^ (row & 7);
      load_lds16(Bb + (size_t)row * 1024 + k0 + gch * 8,
                 (char*)sb + (is * 32 + w * 8) * 128);
    }
    __syncthreads();
#pragma unroll
    for (int ks = 0; ks < 2; ++ks) {
      bf16x8 af[2], bfr[4];
#pragma unroll
      for (int i = 0; i < 2; ++i) {
        int ra = w * 32 + i * 16 + l16;
        af[i] = *reinterpret_cast<const bf16x8*>(sa + ra * 64 +
                                                 (((ks * 4 + q) ^ (ra & 7)) * 8));
      }
#pragma unroll
      for (int j = 0; j < 4; ++j) {
        int rb = j * 16 + l16;
        bfr[j] = *reinterpret_cast<const bf16x8*>(sb + rb * 64 +
                                                  (((ks * 4 + q) ^ (rb & 7)) * 8));
      }
#pragma unroll
      for (int i = 0; i < 2; ++i)
#pragma unroll
        for (int j = 0; j < 4; ++j)
          acc[i][j] =
              __builtin_amdgcn_mfma_f32_16x16x32_bf16(af[i], bfr[j], acc[i][j], 0, 0, 0);
    }
  }

#pragma unroll
  for (int i = 0; i < 2; ++i)
#pragma unroll
    for (int r = 0; r < 4; ++r) {
      int gm = bm * 128 + w * 32 + i * 16 + q * 4 + r;
#pragma unroll
      for (int j = 0; j < 4; ++j) {
        int gn = bn * 64 + j * 16 + l16;
        O[(size_t)gm * 1024 + gn] = acc[i][j][r];
      }
    }
}

// Flash attention v9: mi=2 — each wave owns 32 q-rows (2 strips), block = 128
// q-rows; pairing over 16 q-tiles of 128 -> grid (8, 32) = 256 blocks (1/CU).
// Same staged bytes serve 2x the MFMA work: LDS ops/wave-iter 136 -> 104,
// K/V staging traffic halves. dbuf post-barrier prefetch hides global latency
// (only latency-hiding needed at 1 block/CU). DPP row reductions; per-lane li.
// Q pre-scaled by (1/8)log2e. Q,K: [b,s,h,d]; VT: [b,h,d,s]; AO: [b,s,h,d].
__global__ __launch_bounds__(256) void flash_attn(const uint16_t* __restrict__ Q,
                                                  const uint16_t* __restrict__ K,
                                                  const uint16_t* __restrict__ VT,
                                                  uint16_t* __restrict__ AO) {
  __shared__ uint16_t ksm[2][128 * 64];  // 32 KiB (rows=s, 128B/row, 8-chunk swz)
  __shared__ uint16_t vsm[2][64 * 128];  // 32 KiB (rows=d, 256B/row, 16-chunk swz)
  __shared__ uint16_t psm[4][32 * 128];  // 32 KiB per-wave P (32 rows x 256B)

  const int tid = threadIdx.x;
  const int lane = tid & 63, w = tid >> 6;
  const int q = lane >> 4, l16 = lane & 15;
  const int p = blockIdx.x;   // pair index 0..7 -> 128-row q-tiles {p, 15-p}
  const int bh = blockIdx.y;
  const int b = bh >> 4, h = bh & 15;

  const size_t baseBS = (size_t)b * 2048 * 1024 + h * 64;
  const size_t baseVT = (size_t)bh * 64 * 2048;
  uint16_t* pw = psm[w];
  const f32x4 z4 = {0.f, 0.f, 0.f, 0.f};

  // stage one 128-seq K tile (128x64) + V^T tile (64x128) into buf
  auto stage = [&](int buf, int kt) {
#pragma unroll
    for (int is = 0; is < 4; ++is) {  // ksm: 4 steps x 32 rows (8 rows/wave)
      int row = is * 32 + (tid >> 3);
      int gch = (tid & 7) ^ (row & 7);
      load_lds16(K + baseBS + (size_t)(kt * 128 + row) * 1024 + gch * 8,
                 (char*)ksm[buf] + (is * 32 + w * 8) * 128);
    }
#pragma unroll
    for (int is = 0; is < 4; ++is) {  // vsm: 4 steps x 16 rows (4 rows/wave)
      int row = is * 16 + (tid >> 4);
      int gch = (tid & 15) ^ (row & 15);
      load_lds16(VT + baseVT + (size_t)row * 2048 + kt * 128 + gch * 8,
                 (char*)vsm[buf] + (is * 16 + w * 4) * 256);
    }
  };

  for (int t = 0; t < 2; ++t) {
    const int qt = t ? (15 - p) : p;       // 128-row q-tile index
    const int r0 = qt * 128 + w * 32;      // wave's first q-row
    const int nkt = qt + 1;                // 128-col k-tiles up to diagonal

    // Q fragments (A-layout m=lane&15, k=quad*8+j); Q pre-scaled by (1/8)log2e
    bf16x8 qf[2][2];
#pragma unroll
    for (int mi = 0; mi < 2; ++mi)
#pragma unroll
      for (int ks = 0; ks < 2; ++ks)
        qf[mi][ks] = *reinterpret_cast<const bf16x8*>(
            Q + baseBS + (size_t)(r0 + mi * 16 + l16) * 1024 + ks * 32 + q * 8);

    f32x4 oa[2][4];
#pragma unroll
    for (int mi = 0; mi < 2; ++mi)
#pragma unroll
      for (int di = 0; di < 4; ++di) oa[mi][di] = z4;
    float m2[2][4], li[2][4];
#pragma unroll
    for (int mi = 0; mi < 2; ++mi)
#pragma unroll
      for (int r = 0; r < 4; ++r) { m2[mi][r] = -1e30f; li[mi][r] = 0.f; }

    __syncthreads();  // protect buf0 from previous t's readers
    stage(0, 0);

    for (int kt = 0; kt < nkt; ++kt) {
      const int cur = kt & 1;
      __syncthreads();  // tile kt resident (own loads drained) + wave sync
      if (kt + 1 < nkt) stage(cur ^ 1, kt + 1);  // prefetch flies during body

      // S = Q K^T over 128 cols x 32 rows
      f32x4 sc[2][8];
#pragma unroll
      for (int mi = 0; mi < 2; ++mi)
#pragma unroll
        for (int nj = 0; nj < 8; ++nj) sc[mi][nj] = z4;
#pragma unroll
      for (int ks = 0; ks < 2; ++ks) {
        bf16x8 kf[8];
#pragma unroll
        for (int nj = 0; nj < 8; ++nj) {
          int rk = nj * 16 + l16;
          kf[nj] = *reinterpret_cast<const bf16x8*>(ksm[cur] + rk * 64 +
                                                    (((ks * 4 + q) ^ (rk & 7)) * 8));
        }
#pragma unroll
        for (int mi = 0; mi < 2; ++mi)
#pragma unroll
          for (int nj = 0; nj < 8; ++nj)
            sc[mi][nj] =
                __builtin_amdgcn_mfma_f32_16x16x32_bf16(qf[mi][ks], kf[nj], sc[mi][nj], 0, 0, 0);
      }

      if (kt == nkt - 1) {  // diagonal tile: causal mask
#pragma unroll
        for (int mi = 0; mi < 2; ++mi)
#pragma unroll
          for (int nj = 0; nj < 8; ++nj)
#pragma unroll
            for (int r = 0; r < 4; ++r) {
              int col = kt * 128 + nj * 16 + l16;
              int row = r0 + mi * 16 + q * 4 + r;
              if (col > row) sc[mi][nj][r] = -1e30f;
            }
      }

      // online softmax per strip: row max over 8 nj then DPP 16-lane butterfly
      float alpha[2][4];
#pragma unroll
      for (int mi = 0; mi < 2; ++mi)
#pragma unroll
        for (int r = 0; r < 4; ++r) {
          float v = fmaxf(
              fmaxf(fmaxf(sc[mi][0][r], sc[mi][1][r]), fmaxf(sc[mi][2][r], sc[mi][3][r])),
              fmaxf(fmaxf(sc[mi][4][r], sc[mi][5][r]), fmaxf(sc[mi][6][r], sc[mi][7][r])));
          v = rowmax16(v);
          float mn = fmaxf(m2[mi][r], v);
          alpha[mi][r] = fexp2(m2[mi][r] - mn);
          m2[mi][r] = mn;
          li[mi][r] *= alpha[mi][r];
        }

      // P = 2^(S - m); per-lane li; wave-private LDS round-trip (256B rows,
      // 16-chunk swizzle keyed by row&15)
#pragma unroll
      for (int mi = 0; mi < 2; ++mi)
#pragma unroll
        for (int nj = 0; nj < 8; ++nj)
#pragma unroll
          for (int r = 0; r < 4; ++r) {
            float pv = fexp2(sc[mi][nj][r] - m2[mi][r]);
            li[mi][r] += pv;
            int pr = mi * 16 + q * 4 + r;
            int pc = nj * 16 + l16;
            pw[pr * 128 + (((pc >> 3) ^ (pr & 15)) * 8) + (pc & 7)] = f2bf_trunc(pv);
          }

#pragma unroll
      for (int mi = 0; mi < 2; ++mi)
#pragma unroll
        for (int di = 0; di < 4; ++di)
#pragma unroll
          for (int r = 0; r < 4; ++r) oa[mi][di][r] *= alpha[mi][r];

      // O += P V over K-dim 128 in 4 chunks (same-wave psm RAW; vsm barrier-guarded)
#pragma unroll
      for (int ks = 0; ks < 4; ++ks) {
        bf16x8 pf[2];
#pragma unroll
        for (int mi = 0; mi < 2; ++mi) {
          int pr = mi * 16 + l16;
          pf[mi] = *reinterpret_cast<const bf16x8*>(pw + pr * 128 +
                                                    (((ks * 4 + q) ^ (pr & 15)) * 8));
        }
        bf16x8 vf[4];
#pragma unroll
        for (int di = 0; di < 4; ++di) {
          int vr = di * 16 + l16;
          vf[di] = *reinterpret_cast<const bf16x8*>(vsm[cur] + vr * 128 +
                                                    (((ks * 4 + q) ^ (vr & 15)) * 8));
        }
#pragma unroll
        for (int mi = 0; mi < 2; ++mi)
#pragma unroll
          for (int di = 0; di < 4; ++di)
            oa[mi][di] =
                __builtin_amdgcn_mfma_f32_16x16x32_bf16(pf[mi], vf[di], oa[mi][di], 0, 0, 0);
      }
    }

    // post-loop row-sum (DPP) and store
#pragma unroll
    for (int mi = 0; mi < 2; ++mi)
#pragma unroll
      for (int r = 0; r < 4; ++r) {
        float inv = 1.f / rowsum16(li[mi][r]);
        int gm = r0 + mi * 16 + q * 4 + r;
#pragma unroll
        for (int di = 0; di < 4; ++di)
          AO[baseBS + (size_t)gm * 1024 + di * 16 + l16] = f2bf(oa[mi][di][r] * inv);
      }
  }
}

extern "C" void kernel_launch(void* const* d_in, const int* in_sizes, int n_in,
                              void* d_out, int out_size, void* d_ws, size_t ws_size,
                              hipStream_t stream) {
  (void)in_sizes; (void)n_in; (void)out_size; (void)ws_size;
  const float* x = (const float*)d_in[0];
  const int* tokpos = (const int*)d_in[1];
  const float* wq = (const float*)d_in[2];
  const float* wk = (const float*)d_in[3];
  const float* wv = (const float*)d_in[4];
  const float* wo = (const float*)d_in[5];
  float* out = (float*)d_out;

  // workspace layout (bf16 elements) — total 48 MiB (no overflow).
  uint16_t* ws = (uint16_t*)d_ws;
  uint16_t* xb = ws;                   // 4096*1024
  uint16_t* wqb = xb + 4194304;        // wq|wk|wv|wo contiguous, 1M each
  uint16_t* wob = wqb + 3145728;
  uint16_t* Qb = wob + 1048576;        // [b,s,h,d]; Kb at +4194304
  uint16_t* VTb = Qb + 8388608;        // [b,h,d,s]
  uint16_t* AOb = VTb + 4194304;       // [b,s,h,d]
  // rtab OVERLAPS the AOb region (512 KiB at its base): built by cvt_all,
  // read by gemm_qkv, dead before flash_attn overwrites all of AOb.
  float2* rtab = (float2*)AOb;

  cvt_all<<<8448, 256, 0, stream>>>(x, wq, wk, wv, wo, tokpos, xb, rtab);

  gemm_qkv<<<dim3(24, 32), 256, 0, stream>>>(xb, wqb, Qb, VTb, rtab);

  flash_attn<<<dim3(8, 32), 256, 0, stream>>>(Qb, Qb + 4194304, VTb, AOb);

  gemm_out<<<dim3(16, 32), 256, 0, stream>>>(AOb, wob, out);
}